// Round 5
// baseline (337.979 us; speedup 1.0000x reference)
//
#include <hip/hip_runtime.h>

// B=4, H=8, S=1024, D=512, D_K=64. Inputs fp32 (mask int32); outputs (out, bias) fp32.
// Internal compute: bf16 MFMA (tolerance is ~2% of global absmax; bf16 chain err << that).

using bf16x8 = __attribute__((ext_vector_type(8))) __bf16;
using floatx4 = __attribute__((ext_vector_type(4))) float;

__device__ __forceinline__ unsigned short f2bf(float f) {
  union { float f; unsigned int i; } x; x.f = f;
  unsigned int i = x.i;
  return (unsigned short)((i + 0x7FFFu + ((i >> 16) & 1u)) >> 16);
}

// async global->LDS, 16 B per lane (guide §5: width=16 is the fast path).
__device__ __forceinline__ void gl2lds16(const void* g, void* l) {
  __builtin_amdgcn_global_load_lds(
      (const __attribute__((address_space(1))) unsigned int*)g,
      (__attribute__((address_space(3))) unsigned int*)l, 16, 0, 0);
}

// ---------------------------------------------------------------------------
// Kernel 0 (fused streaming prep): mask pack + bias copy + bf16 converts.
// One grid-stride streaming kernel, 2048 blocks x 256 = 524288 threads.
//  - mask [4,1024,1024] int32 (16.8 MB): 8 ints/thread -> 1 byte of bits.
//  - bias copy 128 MiB: 16 x float4/thread, contiguous, nt stores (write
//    stream must not evict bias/mask from L3; reads stay plain so L3 retains
//    bias for the softmax kernel that re-reads it).
//  - value/W_v/W_o fp32 -> bf16.
// Moving the copy OUT of softmax separates the 128 MiB write stream from the
// latency-sensitive softmax (and finally makes the other kernels visible in
// the top-5 profile: R1-R4 showed only softmax_pv at ~95 us while ~224 us hid
// in dispatches below it).
// ---------------------------------------------------------------------------
__global__ __launch_bounds__(256) void stream_prep_kernel(const int* __restrict__ mask,
                                                          const float* __restrict__ bias,
                                                          const float* __restrict__ value,
                                                          const float* __restrict__ W_v,
                                                          const float* __restrict__ W_o,
                                                          unsigned char* __restrict__ mbits,
                                                          float* __restrict__ bias_out,
                                                          unsigned short* __restrict__ val_bf,
                                                          unsigned short* __restrict__ wv_bf,
                                                          unsigned short* __restrict__ wo_bf) {
  const int T = 2048 * 256;              // total threads
  int tid = blockIdx.x * 256 + threadIdx.x;

  // ---- mask pack: 8 consecutive ints -> 1 byte (little-endian bit order) ----
  {
    size_t base = (size_t)tid * 8;
    int4 m0 = *(const int4*)(mask + base);
    int4 m1 = *(const int4*)(mask + base + 4);
    unsigned int by = (m0.x != 0) | ((m0.y != 0) << 1) | ((m0.z != 0) << 2) | ((m0.w != 0) << 3) |
                      ((m1.x != 0) << 4) | ((m1.y != 0) << 5) | ((m1.z != 0) << 6) | ((m1.w != 0) << 7);
    mbits[tid] = (unsigned char)by;
  }

  // ---- bias copy: 33.55M floats = 16 iters x float4/thread ----
#pragma unroll 4
  for (int i = 0; i < 16; ++i) {
    size_t idx = ((size_t)i * T + tid) * 4;
    floatx4 v = *(const floatx4*)(bias + idx);                  // plain: retain in L3
    __builtin_nontemporal_store(v, (floatx4*)(bias_out + idx)); // nt: don't evict bias
  }

  // ---- value cvt: 2.097M floats = 1 x float4/thread -> 4 bf16 ----
  {
    floatx4 f = *(const floatx4*)(value + (size_t)tid * 4);
    union { ushort4 v; unsigned short u[4]; } r;
#pragma unroll
    for (int j = 0; j < 4; ++j) r.u[j] = f2bf(f[j]);
    *(ushort4*)(val_bf + (size_t)tid * 4) = r.v;                // plain: L2 for gemm1
  }

  // ---- weight cvt: blocks 0-255 -> W_v, 256-511 -> W_o (block-uniform) ----
  if (tid < 2 * 65536) {
    const float* src = (tid < 65536) ? W_v : W_o;
    unsigned short* dst = (tid < 65536) ? wv_bf : wo_bf;
    int idx = tid & 65535;
    floatx4 f = *(const floatx4*)(src + (size_t)idx * 4);
    union { ushort4 v; unsigned short u[4]; } r;
#pragma unroll
    for (int j = 0; j < 4; ++j) r.u[j] = f2bf(f[j]);
    *(ushort4*)(dst + (size_t)idx * 4) = r.v;
  }
}

// ---------------------------------------------------------------------------
// NT GEMM (all-bf16 inputs): out[m,n] = sum_k A[m,k]*B[n,k] + bias[n].
// M=4096,N=512,K=512. 64x64 tile, 4 waves, BK=64. Async double-buffered LDS
// staging with pre-swizzled global source (rule #21). Unchanged from R4.
// ---------------------------------------------------------------------------
template <int MODE>
__global__ __launch_bounds__(256, 4) void gemm_nt_kernel(const unsigned short* __restrict__ A,
                                                         const unsigned short* __restrict__ Bw,
                                                         const float* __restrict__ bias,
                                                         void* __restrict__ outv,
                                                         int M, int N, int K) {
  __shared__ unsigned short As[2][64 * 64];
  __shared__ unsigned short Bs[2][64 * 64];
  int t = threadIdx.x;
  int m0 = blockIdx.x * 64, n0 = blockIdx.y * 64;
  int wave = t >> 6, l = t & 63, lm = l & 15, quad = l >> 4;
  floatx4 acc[4] = {{0,0,0,0},{0,0,0,0},{0,0,0,0},{0,0,0,0}};

  int cid0 = t, cid1 = 256 + t;
  int r0 = cid0 >> 3, cs0 = cid0 & 7;
  int r1 = cid1 >> 3, cs1 = cid1 & 7;
  const unsigned short* a0p = A  + (size_t)(m0 + r0) * K + ((cs0 ^ (r0 & 7)) * 8);
  const unsigned short* a1p = A  + (size_t)(m0 + r1) * K + ((cs1 ^ (r1 & 7)) * 8);
  const unsigned short* b0p = Bw + (size_t)(n0 + r0) * K + ((cs0 ^ (r0 & 7)) * 8);
  const unsigned short* b1p = Bw + (size_t)(n0 + r1) * K + ((cs1 ^ (r1 & 7)) * 8);
  int lb0 = (0 * 256 + wave * 64) * 8, lb1 = (1 * 256 + wave * 64) * 8;

#define STAGE(buf, kk)                                   \
  do {                                                   \
    gl2lds16(a0p + (kk), &As[(buf)][lb0]);               \
    gl2lds16(a1p + (kk), &As[(buf)][lb1]);               \
    gl2lds16(b0p + (kk), &Bs[(buf)][lb0]);               \
    gl2lds16(b1p + (kk), &Bs[(buf)][lb1]);               \
  } while (0)

  STAGE(0, 0);
  __syncthreads();
  for (int it = 0; it < 8; ++it) {
    int cur = it & 1;
    if (it < 7) STAGE(cur ^ 1, (it + 1) * 64);
#pragma unroll
    for (int ks = 0; ks < 2; ++ks) {
      bf16x8 af = *(const bf16x8*)(&As[cur][0] + (wave * 16 + lm) * 64 + (((ks * 4 + quad) ^ (lm & 7)) * 8));
#pragma unroll
      for (int ct = 0; ct < 4; ++ct) {
        bf16x8 bfr = *(const bf16x8*)(&Bs[cur][0] + (ct * 16 + lm) * 64 + (((ks * 4 + quad) ^ (lm & 7)) * 8));
        acc[ct] = __builtin_amdgcn_mfma_f32_16x16x32_bf16(af, bfr, acc[ct], 0, 0, 0);
      }
    }
    __syncthreads();
  }
#undef STAGE

  if (MODE == 0) {
#pragma unroll
    for (int ct = 0; ct < 4; ++ct) {
#pragma unroll
      for (int rg = 0; rg < 4; ++rg) {
        int mg = m0 + wave * 16 + quad * 4 + rg;   // C/D: row = quad*4+reg
        int ng = n0 + ct * 16 + lm;                // C/D: col = lane&15
        ((float*)outv)[(size_t)mg * N + ng] = acc[ct][rg] + bias[ng];
      }
    }
  } else {
    // vT2 layout: [bh][dblk=d>>4][sch=s>>3][lane=d&15][so=s&7], chunk=16B.
    int mgb = m0 + wave * 16 + quad * 4;
    int bb = mgb >> 10, sp = mgb & 1023;
#pragma unroll
    for (int ct = 0; ct < 4; ++ct) {
      int ng = n0 + ct * 16 + lm;
      int hh = ng >> 6, d = ng & 63;
      float bv = bias[ng];
      union { ushort4 v; unsigned short u[4]; } st;
#pragma unroll
      for (int rg = 0; rg < 4; ++rg) st.u[rg] = f2bf(acc[ct][rg] + bv);
      size_t off = ((((size_t)((bb * 8 + hh) * 4 + (d >> 4)) * 128 + (sp >> 3)) * 16) + (d & 15)) * 8 + (sp & 7);
      *(ushort4*)((unsigned short*)outv + off) = st.v;
    }
  }
}

// ---------------------------------------------------------------------------
// Kernel 2: fused mask + softmax + PV. Fixed-shift softmax (shift 16; masked
// w=-60 -> e^-76, graceful uniform for all-masked rows). The 128 MiB bias
// copy now lives in stream_prep; this kernel only READS bias (L3-warm from
// the copy) and writes the 4 MB xout. If dur doesn't collapse from 95 us,
// the bottleneck is proven to be the bias read path itself.
// ---------------------------------------------------------------------------
__global__ __launch_bounds__(256, 5) void softmax_pv_kernel(const float* __restrict__ bias,
                                                            const unsigned int* __restrict__ mbits,
                                                            const unsigned short* __restrict__ vt,
                                                            unsigned short* __restrict__ xout) {
  __shared__ char smem[16 * 1024 * 2];   // 32 KB: bf16 p tile; later aliased as fp32 reduce buf
  unsigned short* w_tile = (unsigned short*)smem;
  float* red = (float*)smem;             // 4 waves x 16 rows x 64 cols fp32 = 16 KB

  int bid0 = blockIdx.x;
  int bid = (bid0 & 7) * 256 + (bid0 >> 3);   // bijective XCD swizzle (2048 = 8*256)
  int qt = bid & 63, h = (bid >> 6) & 7, b = bid >> 9;
  int q0 = qt * 16;
  int t = threadIdx.x;

  // ---- pass 1: read bias, mask, exp(w-16)->bf16 LDS, sum ----
  int r = t >> 4, c = t & 15;            // 16 lanes per q-row, 4 floats/lane/iter
  int q = q0 + r;
  size_t boff = ((size_t)((b * 8 + h) * 1024 + q)) << 10;
  const float* brow = bias + boff;
  const unsigned int* mrow = mbits + (b * 1024 + q) * 32;

  float sum = 0.f;
#pragma unroll
  for (int i = 0; i < 16; ++i) {
    int k0 = c * 4 + i * 64;
    floatx4 b0 = *(const floatx4*)(brow + k0);                       // plain: L3-hit
    unsigned int nib = (mrow[k0 >> 5] >> (k0 & 31)) & 0xFu;
    union { ushort4 v; unsigned short u[4]; } p;
#pragma unroll
    for (int j = 0; j < 4; ++j) {
      float wv = ((nib >> j) & 1u) ? b0[j] : -60.f;
      float e = __expf(wv - 16.f);
      sum += e;
      p.u[j] = f2bf(e);
    }
    int ch = k0 >> 3, half = (k0 >> 2) & 1;          // 16B chunk + 8B half
    *(ushort4*)(w_tile + r * 1024 + ((ch ^ (r & 7)) * 8) + half * 4) = p.v;
  }
#pragma unroll
  for (int off = 1; off < 16; off <<= 1) sum += __shfl_xor(sum, off, 64);
  float inv = 1.0f / sum;                // all 16 lanes of the row hold it
  __syncthreads();

  // ---- pass 2: PV via MFMA, wave w covers k in [w*256, w*256+256) ----
  int wave = t >> 6, l = t & 63, lm = l & 15, quad = l >> 4;
  floatx4 acc[4] = {{0,0,0,0},{0,0,0,0},{0,0,0,0},{0,0,0,0}};
  const unsigned short* vbase = vt + (size_t)((b * 8 + h)) * 65536;  // vT2 tile, 128 KB
#pragma unroll
  for (int s = 0; s < 8; ++s) {
    int kt = wave * 8 + s;               // k-tile of 32
    int ch = kt * 4 + quad;
    bf16x8 af = *(const bf16x8*)(w_tile + lm * 1024 + ((ch ^ (lm & 7)) * 8));  // A: p[q=lm][k]
#pragma unroll
    for (int ct = 0; ct < 4; ++ct) {     // B: v[k][d=ct*16+lm], 2KB contiguous per instr
      bf16x8 bfr = *(const bf16x8*)(vbase + (((size_t)ct * 128 + ch) * 16 + lm) * 8);
      acc[ct] = __builtin_amdgcn_mfma_f32_16x16x32_bf16(af, bfr, acc[ct], 0, 0, 0);
    }
  }
  __syncthreads();                       // all p-tile reads done before aliasing as `red`
#pragma unroll
  for (int ct = 0; ct < 4; ++ct)
#pragma unroll
    for (int rg = 0; rg < 4; ++rg)
      red[(wave * 16 + quad * 4 + rg) * 64 + ct * 16 + lm] = acc[ct][rg];
  __syncthreads();

  int row = t >> 4, col0 = (t & 15) * 4;   // same row assignment as pass 1 -> reuse `inv`
  union { ushort4 v; unsigned short u[4]; } st;
#pragma unroll
  for (int i = 0; i < 4; ++i) {
    int col = col0 + i;
    float vsum = red[(0 * 16 + row) * 64 + col] + red[(1 * 16 + row) * 64 + col] +
                 red[(2 * 16 + row) * 64 + col] + red[(3 * 16 + row) * 64 + col];
    st.u[i] = f2bf(vsum * inv);
  }
  // x layout [b][q][h][64] == row-major [4096][512] (bf16) for the output GEMM
  *(ushort4*)(xout + (((size_t)(b * 1024 + q0 + row) * 8 + h) * 64 + col0)) = st.v;
}

// ---------------------------------------------------------------------------
extern "C" void kernel_launch(void* const* d_in, const int* in_sizes, int n_in,
                              void* d_out, int out_size, void* d_ws, size_t ws_size,
                              hipStream_t stream) {
  // inputs: 0 query (unused), 1 key (unused), 2 value, 3 bias, 4 mask,
  //         5 W_v, 6 b_v, 7 W_o, 8 b_o   — all fp32 except mask (int32)
  const float* value = (const float*)d_in[2];
  const float* bias  = (const float*)d_in[3];
  const int*   mask  = (const int*)d_in[4];
  const float* W_v   = (const float*)d_in[5];
  const float* b_v   = (const float*)d_in[6];
  const float* W_o   = (const float*)d_in[7];
  const float* b_o   = (const float*)d_in[8];

  float* out = (float*)d_out;                              // [4,1024,512] fp32
  float* bias_out = out + (size_t)4 * 1024 * 512;          // bias copy region, fp32

  char* ws = (char*)d_ws;
  unsigned short* vT     = (unsigned short*)ws;               // vT2 tiled, 4 MB
  unsigned short* val_bf = (unsigned short*)(ws + (4 << 20)); // value bf16 [4096][512], 4 MB
  unsigned short* xbuf   = val_bf;                            // aliased: val_bf dead after gemm1
  unsigned char*  mbits  = (unsigned char*)(ws + (8 << 20));  // 512 KB bit mask
  unsigned short* wv_bf  = (unsigned short*)(ws + (8 << 20) + (512 << 10)); // 512 KB
  unsigned short* wo_bf  = (unsigned short*)(ws + (9 << 20));               // 512 KB

  stream_prep_kernel<<<dim3(2048), 256, 0, stream>>>(mask, bias, value, W_v, W_o,
                                                     mbits, bias_out, val_bf, wv_bf, wo_bf);
  gemm_nt_kernel<1><<<dim3(64, 8), 256, 0, stream>>>(val_bf, wv_bf, b_v, vT, 4096, 512, 512);
  softmax_pv_kernel<<<dim3(2048), 256, 0, stream>>>(bias, (const unsigned int*)mbits, vT, xbuf);
  gemm_nt_kernel<0><<<dim3(64, 8), 256, 0, stream>>>(xbuf, wo_bf, b_o, out, 4096, 512, 512);
}